// Round 7
// baseline (389.404 us; speedup 1.0000x reference)
//
#include <hip/hip_runtime.h>
#include <hip/hip_bf16.h>

typedef unsigned int u32;
using bf16x8 = __attribute__((ext_vector_type(8))) short;
using f32x4  = __attribute__((ext_vector_type(4))) float;

#define QKV_STRIDE 12582912u   // elements per q/k/v tensor (512*3*256*32)
#define WS_NEED    100663296ull
#define MLP_P      392         // padded hid pitch (shorts)

__device__ __forceinline__ float bl(u32 u) { return __uint_as_float(u << 16); }
__device__ __forceinline__ float bh(u32 u) { return __uint_as_float(u & 0xffff0000u); }
__device__ __forceinline__ unsigned short bfbits(float f) {
    __hip_bfloat16 b = __float2bfloat16(f);
    return *(unsigned short*)&b;
}
__device__ __forceinline__ u32 pack2(float f0, float f1) {
    return ((u32)bfbits(f1) << 16) | (u32)bfbits(f0);
}
// load 8 consecutive fp32 -> bf16x8 fragment (16B-aligned source)
__device__ __forceinline__ bf16x8 ldrow(const float* p) {
    float4 a = *(const float4*)p;
    float4 b = *(const float4*)(p + 4);
    union { bf16x8 v; u32 u[4]; } t;
    t.u[0] = pack2(a.x, a.y); t.u[1] = pack2(a.z, a.w);
    t.u[2] = pack2(b.x, b.y); t.u[3] = pack2(b.z, b.w);
    return t.v;
}

#define MFMA(a, b, c) __builtin_amdgcn_mfma_f32_16x16x32_bf16(a, b, c, 0, 0, 0)

// ---------------- guard: ws too small -> sentinel 1000 ----------------
__global__ __launch_bounds__(256) void k_fill(float* __restrict__ out, int n)
{
    int i = blockIdx.x * 256 + threadIdx.x;
    if (i < n) out[i] = 1000.0f;
}

// ---------------- K1: coalesced gather + LayerNorm1 -> h (bf16) [unchanged] ----------------
__global__ __launch_bounds__(256) void k_ln1_c(const float* __restrict__ x,
                                               const float* __restrict__ g1,
                                               const float* __restrict__ b1,
                                               u32* __restrict__ h)
{
    __shared__ float xs[96 * 128];
    __shared__ float ps[256], pss[256], mr[128], rs[128];
    int blk = blockIdx.x;
    int hh = blk & 127, d = (blk >> 7) & 3, bb = blk >> 9;
    long base = (long)bb * 6291456 + (long)d * 16384 + hh * 128;
    for (int i = threadIdx.x; i < 3072; i += 256) {
        int c = i >> 5, w4 = i & 31;
        ((float4*)xs)[i] = *(const float4*)(x + base + (long)c * 65536 + w4 * 4);
    }
    __syncthreads();

    int tid = threadIdx.x, half = tid >> 7, ww = tid & 127;
    int c0 = half * 48;
    float s = 0.f, ssq = 0.f;
    #pragma unroll 8
    for (int c = c0; c < c0 + 48; ++c) {
        float v = xs[c * 128 + ww];
        s += v; ssq += v * v;
    }
    ps[tid] = s; pss[tid] = ssq;
    __syncthreads();
    if (half == 0) {
        float st = ps[ww] + ps[128 + ww], sst = pss[ww] + pss[128 + ww];
        float mean = st * (1.f / 96.f);
        float var  = sst * (1.f / 96.f) - mean * mean;
        mr[ww] = mean; rs[ww] = rsqrtf(var + 1e-5f);
    }
    __syncthreads();
    float mean = mr[ww], rstd = rs[ww];

    int w = (bb << 8) + (hh >> 3) * 16 + (ww >> 3);
    int t = (w << 8) + d * 64 + (hh & 7) * 8 + (ww & 7);
    uint4* hq = (uint4*)(h + (long)t * 48 + half * 24);
    #pragma unroll
    for (int k = 0; k < 6; ++k) {
        int c = c0 + 8 * k;
        u32 q0 = pack2((xs[(c+0)*128+ww]-mean)*rstd*g1[c+0]+b1[c+0],
                       (xs[(c+1)*128+ww]-mean)*rstd*g1[c+1]+b1[c+1]);
        u32 q1 = pack2((xs[(c+2)*128+ww]-mean)*rstd*g1[c+2]+b1[c+2],
                       (xs[(c+3)*128+ww]-mean)*rstd*g1[c+3]+b1[c+3]);
        u32 q2 = pack2((xs[(c+4)*128+ww]-mean)*rstd*g1[c+4]+b1[c+4],
                       (xs[(c+5)*128+ww]-mean)*rstd*g1[c+5]+b1[c+5]);
        u32 q3 = pack2((xs[(c+6)*128+ww]-mean)*rstd*g1[c+6]+b1[c+6],
                       (xs[(c+7)*128+ww]-mean)*rstd*g1[c+7]+b1[c+7]);
        hq[k] = make_uint4(q0, q1, q2, q3);
    }
}

// ---------------- K2: QKV GEMM via MFMA, weights direct from global fp32 ----------------
__global__ __launch_bounds__(256) void k_qkv_m(const __hip_bfloat16* __restrict__ h,
                                               const float* __restrict__ qkvw,
                                               const float* __restrict__ qkvb,
                                               __hip_bfloat16* __restrict__ qkv)
{
    int tid = threadIdx.x;
    int wave = tid >> 6, lane = tid & 63;
    int quad = lane >> 4, l16 = lane & 15;
    int mbase = blockIdx.x * 256 + wave * 64;

    bf16x8 A[4][3];
    #pragma unroll
    for (int mm = 0; mm < 4; ++mm) {
        const __hip_bfloat16* ap = h + (long)(mbase + mm * 16 + l16) * 96 + quad * 8;
        A[mm][0] = *(const bf16x8*)(ap);
        A[mm][1] = *(const bf16x8*)(ap + 32);
        A[mm][2] = *(const bf16x8*)(ap + 64);
    }

    for (int nt = 0; nt < 18; ++nt) {
        int n0 = nt * 16;
        const float* wr = qkvw + (long)(n0 + l16) * 96 + quad * 8;
        bf16x8 B0 = ldrow(wr);
        bf16x8 B1 = ldrow(wr + 32);
        bf16x8 B2 = ldrow(wr + 64);
        int r    = n0 + l16;
        int type = n0 / 96;
        int head = (n0 % 96) / 32;
        int dd   = r & 31;
        float bias = qkvb[r];
        float scl  = (type == 0) ? 0.17677669529663687f : 1.0f;
        long tbase = (long)type * QKV_STRIDE;
        #pragma unroll
        for (int mm = 0; mm < 4; ++mm) {
            f32x4 acc = {0.f, 0.f, 0.f, 0.f};
            acc = MFMA(A[mm][0], B0, acc);
            acc = MFMA(A[mm][1], B1, acc);
            acc = MFMA(A[mm][2], B2, acc);
            int tok0 = mbase + mm * 16 + quad * 4;
            int w = tok0 >> 8, nn = tok0 & 255;
            long dst0 = tbase + (long)(w * 3 + head) * 8192 + nn * 32 + dd;
            #pragma unroll
            for (int rg = 0; rg < 4; ++rg)
                qkv[dst0 + (long)rg * 32] = __float2bfloat16((acc[rg] + bias) * scl);
        }
    }
}

// ---------------- K3: window attention via MFMA [unchanged] ----------------
__global__ __launch_bounds__(256) void k_attn_m(const __hip_bfloat16* __restrict__ qkv,
                                                const float* __restrict__ btab,
                                                __hip_bfloat16* __restrict__ o)
{
    __shared__ short vt[32 * 264];
    __shared__ short pm[4 * 16 * 264];
    __shared__ float bsT[31 * 33];
    int wh = blockIdx.x, head = wh % 3, w = wh / 3;
    int tid = threadIdx.x;

    const u32* vg = (const u32*)(qkv + 2u * QKV_STRIDE + (long)wh * 8192);
    for (int idx = tid; idx < 4096; idx += 256) {
        u32 pv = vg[idx];
        int kr = idx >> 4, d0 = (idx & 15) * 2;
        vt[d0 * 264 + kr]       = (short)(pv & 0xffffu);
        vt[(d0 + 1) * 264 + kr] = (short)(pv >> 16);
    }
    for (int idx = tid; idx < 961; idx += 256) {
        int c2 = idx / 31, r2 = idx - c2 * 31;
        bsT[c2 * 33 + r2] = btab[(r2 * 31 + c2) * 3 + head];
    }
    __syncthreads();

    int wave = tid >> 6, lane = tid & 63, quad = lane >> 4, l16 = lane & 15;
    const __hip_bfloat16* qb = qkv + (long)wh * 8192;
    const __hip_bfloat16* kb = qkv + QKV_STRIDE + (long)wh * 8192;
    short* pmw = &pm[wave * 16 * 264];

    bf16x8 kf[16];
    #pragma unroll
    for (int kt = 0; kt < 16; ++kt)
        kf[kt] = *(const bf16x8*)(kb + (kt * 16 + l16) * 32 + quad * 8);

    for (int g = 0; g < 4; ++g) {
        int qg = wave * 4 + g;
        bf16x8 qf = *(const bf16x8*)(qb + (qg * 16 + l16) * 32 + quad * 8);
        f32x4 s[16];
        #pragma unroll
        for (int kt = 0; kt < 16; ++kt) {
            f32x4 z = {0.f, 0.f, 0.f, 0.f};
            s[kt] = MFMA(kf[kt], qf, z);
        }
        #pragma unroll
        for (int rg = 0; rg < 4; ++rg) {
            const float* bp2 = &bsT[(l16 - quad * 4 + 15 - rg) * 33 + qg + 15];
            #pragma unroll
            for (int kt = 0; kt < 16; ++kt)
                s[kt][rg] += bp2[-kt];
        }
        float mx = -1e30f;
        #pragma unroll
        for (int kt = 0; kt < 16; ++kt)
            #pragma unroll
            for (int rg = 0; rg < 4; ++rg) mx = fmaxf(mx, s[kt][rg]);
        mx = fmaxf(mx, __shfl_xor(mx, 16));
        mx = fmaxf(mx, __shfl_xor(mx, 32));
        float lsum = 0.f;
        #pragma unroll
        for (int kt = 0; kt < 16; ++kt)
            #pragma unroll
            for (int rg = 0; rg < 4; ++rg) {
                float p = __expf(s[kt][rg] - mx);
                s[kt][rg] = p; lsum += p;
            }
        lsum += __shfl_xor(lsum, 16);
        lsum += __shfl_xor(lsum, 32);
        float inv = 1.f / lsum;
        #pragma unroll
        for (int kt = 0; kt < 16; ++kt)
            #pragma unroll
            for (int rg = 0; rg < 4; ++rg)
                pmw[l16 * 264 + kt * 16 + quad * 4 + rg] = (short)bfbits(s[kt][rg] * inv);
        f32x4 a0 = {0.f, 0.f, 0.f, 0.f}, a1 = {0.f, 0.f, 0.f, 0.f};
        #pragma unroll
        for (int k2 = 0; k2 < 8; ++k2) {
            bf16x8 pf = *(const bf16x8*)&pmw[l16 * 264 + k2 * 32 + quad * 8];
            bf16x8 v0 = *(const bf16x8*)&vt[l16 * 264 + k2 * 32 + quad * 8];
            bf16x8 v1 = *(const bf16x8*)&vt[(16 + l16) * 264 + k2 * 32 + quad * 8];
            a0 = MFMA(pf, v0, a0);
            a1 = MFMA(pf, v1, a1);
        }
        #pragma unroll
        for (int rg = 0; rg < 4; ++rg) {
            int qrow = qg * 16 + quad * 4 + rg;
            __hip_bfloat16* op = o + (long)(w * 256 + qrow) * 96 + head * 32;
            op[l16]      = __float2bfloat16(a0[rg]);
            op[16 + l16] = __float2bfloat16(a1[rg]);
        }
    }
}

// ---------------- K4a: proj -> pbuf (bf16), weights direct from global ----------------
__global__ __launch_bounds__(256) void k_proj_nr(const __hip_bfloat16* __restrict__ o,
                                                 const float* __restrict__ pw,
                                                 const float* __restrict__ pb,
                                                 __hip_bfloat16* __restrict__ pbuf)
{
    int tid = threadIdx.x;
    int wave = tid >> 6, lane = tid & 63;
    int quad = lane >> 4, l16 = lane & 15;
    int mbase = blockIdx.x * 256 + wave * 64;

    bf16x8 A[4][3];
    #pragma unroll
    for (int mm = 0; mm < 4; ++mm) {
        const __hip_bfloat16* ap = o + (long)(mbase + mm * 16 + l16) * 96 + quad * 8;
        A[mm][0] = *(const bf16x8*)(ap);
        A[mm][1] = *(const bf16x8*)(ap + 32);
        A[mm][2] = *(const bf16x8*)(ap + 64);
    }

    for (int nt = 0; nt < 6; ++nt) {
        int n0 = nt * 16;
        const float* wr = pw + (long)(n0 + l16) * 96 + quad * 8;
        bf16x8 B0 = ldrow(wr);
        bf16x8 B1 = ldrow(wr + 32);
        bf16x8 B2 = ldrow(wr + 64);
        int c = n0 + l16;
        float bias = pb[c];
        #pragma unroll
        for (int mm = 0; mm < 4; ++mm) {
            f32x4 acc = {0.f, 0.f, 0.f, 0.f};
            acc = MFMA(A[mm][0], B0, acc);
            acc = MFMA(A[mm][1], B1, acc);
            acc = MFMA(A[mm][2], B2, acc);
            int tok0 = mbase + mm * 16 + quad * 4;
            #pragma unroll
            for (int rg = 0; rg < 4; ++rg)
                pbuf[(long)(tok0 + rg) * 96 + c] = __float2bfloat16(acc[rg] + bias);
        }
    }
}

// ---------------- K4b: residual + LN2 -> t2 (bf16), h2 (bf16) [unchanged] ----------------
__global__ __launch_bounds__(256) void k_addln2(const float* __restrict__ x,
                                                const __hip_bfloat16* __restrict__ pbuf,
                                                const float* __restrict__ g2,
                                                const float* __restrict__ b2,
                                                u32* __restrict__ t2,
                                                u32* __restrict__ h2)
{
    __shared__ float xs[96 * 128];
    __shared__ float ps[256], pss[256], mr[128], rs[128];
    int blk = blockIdx.x;
    int hh = blk & 127, d = (blk >> 7) & 3, bb = blk >> 9;
    long base = (long)bb * 6291456 + (long)d * 16384 + hh * 128;
    for (int i = threadIdx.x; i < 3072; i += 256) {
        int c = i >> 5, w4 = i & 31;
        ((float4*)xs)[i] = *(const float4*)(x + base + (long)c * 65536 + w4 * 4);
    }
    __syncthreads();

    int tid = threadIdx.x, half = tid >> 7, ww = tid & 127;
    int c0 = half * 48;
    int w = (bb << 8) + (hh >> 3) * 16 + (ww >> 3);
    int t = (w << 8) + d * 64 + (hh & 7) * 8 + (ww & 7);

    const u32* pr = (const u32*)pbuf + (long)t * 48 + half * 24;
    float pv[48];
    float s = 0.f, ssq = 0.f;
    #pragma unroll
    for (int k = 0; k < 24; ++k) {
        u32 u = pr[k];
        float v0 = bl(u) + xs[(c0 + 2 * k) * 128 + ww];
        float v1 = bh(u) + xs[(c0 + 2 * k + 1) * 128 + ww];
        pv[2 * k] = v0; pv[2 * k + 1] = v1;
        s += v0 + v1; ssq += v0 * v0 + v1 * v1;
    }
    ps[tid] = s; pss[tid] = ssq;
    __syncthreads();
    if (half == 0) {
        float st = ps[ww] + ps[128 + ww], sst = pss[ww] + pss[128 + ww];
        float mean = st * (1.f / 96.f);
        float var  = sst * (1.f / 96.f) - mean * mean;
        mr[ww] = mean; rs[ww] = rsqrtf(var + 1e-5f);
    }
    __syncthreads();
    float mean = mr[ww], rstd = rs[ww];

    uint4* t2q = (uint4*)(t2 + (long)t * 48 + half * 24);
    uint4* hq  = (uint4*)(h2 + (long)t * 48 + half * 24);
    #pragma unroll
    for (int k = 0; k < 6; ++k) {
        int c = c0 + 8 * k;
        u32 t0v = pack2(pv[8*k+0], pv[8*k+1]);
        u32 t1v = pack2(pv[8*k+2], pv[8*k+3]);
        u32 t2v = pack2(pv[8*k+4], pv[8*k+5]);
        u32 t3v = pack2(pv[8*k+6], pv[8*k+7]);
        t2q[k] = make_uint4(t0v, t1v, t2v, t3v);
        u32 q0 = pack2((pv[8*k+0]-mean)*rstd*g2[c+0]+b2[c+0],
                       (pv[8*k+1]-mean)*rstd*g2[c+1]+b2[c+1]);
        u32 q1 = pack2((pv[8*k+2]-mean)*rstd*g2[c+2]+b2[c+2],
                       (pv[8*k+3]-mean)*rstd*g2[c+3]+b2[c+3]);
        u32 q2 = pack2((pv[8*k+4]-mean)*rstd*g2[c+4]+b2[c+4],
                       (pv[8*k+5]-mean)*rstd*g2[c+5]+b2[c+5]);
        u32 q3 = pack2((pv[8*k+6]-mean)*rstd*g2[c+6]+b2[c+6],
                       (pv[8*k+7]-mean)*rstd*g2[c+7]+b2[c+7]);
        hq[k] = make_uint4(q0, q1, q2, q3);
    }
}

// ---------------- K5: fused MLP: fc1 + GELU + fc2 + residual -> out ----------------
// block = 64 tokens (4 waves x 16); m-tile lives in LDS, never in HBM.
__global__ __launch_bounds__(256) void k_mlp(const __hip_bfloat16* __restrict__ h2,
                                             const float* __restrict__ fw1,
                                             const float* __restrict__ fb1,
                                             const float* __restrict__ fw2,
                                             const float* __restrict__ fb2,
                                             const __hip_bfloat16* __restrict__ t2,
                                             float* __restrict__ out)
{
    __shared__ short mt[4 * 16 * MLP_P];   // 50176 B: per-wave m [tok16][hid384 pad 392]
    __shared__ short wb[16 * MLP_P];       // 12544 B: fc1 phase [64][96] / fc2 phase [16][392]
    int tid = threadIdx.x, wave = tid >> 6, lane = tid & 63;
    int quad = lane >> 4, l16 = lane & 15;
    int tok0 = blockIdx.x * 64 + wave * 16;

    const __hip_bfloat16* ap = h2 + (long)(tok0 + l16) * 96 + quad * 8;
    bf16x8 A0 = *(const bf16x8*)(ap);
    bf16x8 A1 = *(const bf16x8*)(ap + 32);
    bf16x8 A2 = *(const bf16x8*)(ap + 64);
    short* mw = &mt[wave * 16 * MLP_P];
    const float is2 = 0.70710678118654752440f;

    // ---- fc1: 6 phases x 64 hidden ----
    for (int p = 0; p < 6; ++p) {
        if (p) __syncthreads();
        const float* src = fw1 + p * 64 * 96;
        for (int i = tid; i < 6144; i += 256) wb[i] = (short)bfbits(src[i]);
        __syncthreads();
        #pragma unroll
        for (int nt = 0; nt < 4; ++nt) {
            const short* bp = &wb[(nt * 16 + l16) * 96 + quad * 8];
            bf16x8 B0 = *(const bf16x8*)(bp);
            bf16x8 B1 = *(const bf16x8*)(bp + 32);
            bf16x8 B2 = *(const bf16x8*)(bp + 64);
            int r = p * 64 + nt * 16 + l16;
            float bias = fb1[r];
            f32x4 acc = {0.f, 0.f, 0.f, 0.f};
            acc = MFMA(A0, B0, acc);
            acc = MFMA(A1, B1, acc);
            acc = MFMA(A2, B2, acc);
            #pragma unroll
            for (int rg = 0; rg < 4; ++rg) {
                float v = acc[rg] + bias;
                v = 0.5f * v * (1.f + erff(v * is2));
                mw[(quad * 4 + rg) * MLP_P + r] = (short)bfbits(v);
            }
        }
    }
    __syncthreads();                       // fc1 complete block-wide

    // m-frags for this wave's 16 tokens (own LDS region)
    bf16x8 M[12];
    #pragma unroll
    for (int kc = 0; kc < 12; ++kc)
        M[kc] = *(const bf16x8*)&mw[l16 * MLP_P + kc * 32 + quad * 8];

    // ---- fc2: 6 phases x 16 out-channels ----
    for (int q = 0; q < 6; ++q) {
        if (q) __syncthreads();
        const float* src = fw2 + q * 16 * 384;
        for (int i = tid; i < 6144; i += 256) {
            int rr = i / 384, cc = i - rr * 384;
            wb[rr * MLP_P + cc] = (short)bfbits(src[i]);
        }
        __syncthreads();
        bf16x8 B[12];
        #pragma unroll
        for (int kc = 0; kc < 12; ++kc)
            B[kc] = *(const bf16x8*)&wb[l16 * MLP_P + kc * 32 + quad * 8];
        f32x4 acc = {0.f, 0.f, 0.f, 0.f};
        #pragma unroll
        for (int kc = 0; kc < 12; ++kc)
            acc = MFMA(M[kc], B[kc], acc);
        int c = q * 16 + l16;
        float bias = fb2[c];
        #pragma unroll
        for (int rg = 0; rg < 4; ++rg) {
            long g = (long)(tok0 + quad * 4 + rg) * 96 + c;
            out[g] = __bfloat162float(t2[g]) + acc[rg] + bias;
        }
    }
}

extern "C" void kernel_launch(void* const* d_in, const int* in_sizes, int n_in,
                              void* d_out, int out_size, void* d_ws, size_t ws_size,
                              hipStream_t stream)
{
    const float* x     = (const float*)d_in[0];
    const float* qkvw  = (const float*)d_in[1];
    const float* qkvb  = (const float*)d_in[2];
    const float* projw = (const float*)d_in[3];
    const float* projb = (const float*)d_in[4];
    const float* btab  = (const float*)d_in[5];
    const float* ln1g  = (const float*)d_in[6];
    const float* ln1b  = (const float*)d_in[7];
    const float* ln2g  = (const float*)d_in[8];
    const float* ln2b  = (const float*)d_in[9];
    const float* fc1w  = (const float*)d_in[10];
    const float* fc1b  = (const float*)d_in[11];
    const float* fc2w  = (const float*)d_in[12];
    const float* fc2b  = (const float*)d_in[13];
    float* out = (float*)d_out;

    if (ws_size < WS_NEED) {
        k_fill<<<49152, 256, 0, stream>>>(out, out_size);
        return;
    }

    // ws lifetimes (96 MiB):
    //  [0,72)  : qkv(bf16) -> pbuf bf16 [0,24)
    //  [48,72) : t2 bf16
    //  [72,96) : h(bf16) -> o(bf16) -> h2(bf16)
    char* ws = (char*)d_ws;
    __hip_bfloat16* qkvB  = (__hip_bfloat16*)(ws);
    __hip_bfloat16* pbuf  = (__hip_bfloat16*)(ws);
    __hip_bfloat16* t2buf = (__hip_bfloat16*)(ws + 50331648);
    __hip_bfloat16* hbuf  = (__hip_bfloat16*)(ws + 75497472);
    __hip_bfloat16* obuf  = hbuf;
    __hip_bfloat16* h2buf = hbuf;

    k_ln1_c  <<<1024, 256, 0, stream>>>(x, ln1g, ln1b, (u32*)hbuf);
    k_qkv_m  <<<512,  256, 0, stream>>>(hbuf, qkvw, qkvb, qkvB);
    k_attn_m <<<1536, 256, 0, stream>>>(qkvB, btab, obuf);
    k_proj_nr<<<512,  256, 0, stream>>>(obuf, projw, projb, pbuf);
    k_addln2 <<<1024, 256, 0, stream>>>(x, pbuf, ln2g, ln2b, (u32*)t2buf, (u32*)h2buf);
    k_mlp    <<<2048, 256, 0, stream>>>(h2buf, fc1w, fc1b, fc2w, fc2b, t2buf, out);
}